// Round 3
// baseline (118593.176 us; speedup 1.0000x reference)
//
#include <hip/hip_runtime.h>
#include <stdint.h>

// Seq2Seq decoder (2-layer LSTM + Luong attention), B=64, T=256, S=512, H=512.
// Round 3: ALL-f32 VALU implementation (no MFMA, no bf16 anywhere).
//   Rationale: R1/R2 error identical (~1.96) despite activation-precision fix
//   => enc/weight bf16 noise drives chaotic divergence of the recurrence.
//   This round removes every non-f32 datapath AND every layout-assumption risk.
// Persistent kernel, hand-rolled device-scope grid barrier, 5 phases/step:
//   A: z1=[x_t,attn,h1]@[ki1;kr1]+b1 -> LSTM1   (K=1536, N=2048)
//   B: z2=[h1new,h2]@[ki2;kr2]+b2   -> LSTM2    (K=1024, N=2048)
//   C: q = h2new @ Wm^T                          (K=512,  N=1024)
//   D: flash attention partials over s (scores = enc . q, exact reassoc)
//   E: attn_out = [h2new, ctx]@Wa  (ctx combined from partials during staging)

typedef float f32x2 __attribute__((ext_vector_type(2)));
typedef float f32x4 __attribute__((ext_vector_type(4)));

#define NWG  256
#define NTHR 256

struct Params {
  const float* tgt;    // [64][256][512]
  const float* mask;   // [64][512] (1.0 = masked)
  const float* ki1;    // [1024][2048]
  const float* kr1;    // [512][2048]
  const float* b1;     // [2048]
  const float* ki2;    // [512][2048]
  const float* kr2;    // [512][2048]
  const float* b2;     // [2048]
  const float* Wa;     // [1536][512] (raw input, used directly)
  const float* WmT;    // [512][1024] = W_memory^T (prepped)
  const float* enc;    // [64][512][1024] f32 (raw input, used directly)
  float *h1a,*h1b,*h2a,*h2b;  // ping-pong [64][512]
  float *attn;                // [64][512]
  float *q;                   // [64][1024]
  float *c1,*c2;              // [64][512]
  float *part;                // [256][1032]  (M, L, ctx[1024]) per (b, s-group)
  unsigned *cnt,*gen;
  float *out;                 // [64][256][512]
};

__device__ __forceinline__ float sigmf(float x){ return 1.f/(1.f+__expf(-x)); }

// -------- grid barrier (device scope; 256 WGs, 1/CU, co-resident) --------
__device__ void gbar(unsigned* cnt, unsigned* gen){
  __syncthreads();
  if (threadIdx.x == 0){
    unsigned g = __hip_atomic_load(gen, __ATOMIC_RELAXED, __HIP_MEMORY_SCOPE_AGENT);
    unsigned a = __hip_atomic_fetch_add(cnt, 1u, __ATOMIC_ACQ_REL, __HIP_MEMORY_SCOPE_AGENT) + 1u;
    if (a == NWG){
      __hip_atomic_store(cnt, 0u, __ATOMIC_RELAXED, __HIP_MEMORY_SCOPE_AGENT);
      __hip_atomic_fetch_add(gen, 1u, __ATOMIC_RELEASE, __HIP_MEMORY_SCOPE_AGENT);
    } else {
      while (__hip_atomic_load(gen, __ATOMIC_ACQUIRE, __HIP_MEMORY_SCOPE_AGENT) == g)
        __builtin_amdgcn_s_sleep(2);
    }
  }
  __syncthreads();
}

// ======== phases A/B: GEMM + fused LSTM epilogue ========
// WG owns 2 h-columns h0=wg*2 across all 4 gates (n = g*512 + h0 + j).
// Thread: b = lane, k-quarter = wave. Chunked LDS staging of the A matrix.
template<int PHASE>
__device__ void lstm_phase(const Params& P, int t, int rp, float* xs, float* zbuf){
  const int wg = blockIdx.x, tid = threadIdx.x;
  const int lane = tid & 63, wv = tid >> 6;
  const int h0 = wg << 1;
  const int NCH = (PHASE==1) ? 6 : 4;
  const float* h1r = (rp==0) ? P.h1a : P.h1b;
  float* h1w       = (rp==0) ? P.h1b : P.h1a;
  const float* h2r = (rp==0) ? P.h2a : P.h2b;
  float* h2w       = (rp==0) ? P.h2b : P.h2a;

  float acc[4][2];
  #pragma unroll
  for (int g=0; g<4; ++g){ acc[g][0]=0.f; acc[g][1]=0.f; }

  for (int c=0; c<NCH; ++c){
    __syncthreads();                        // protect xs WAR
    // stage [64][256] slice of the (virtual) A matrix
    for (int i=tid; i<64*256; i+=NTHR){
      int r = i>>8, col = i&255;
      float v;
      if (PHASE==1){
        if (c<2)      v = P.tgt[(((size_t)r*256 + t)<<9) + (c<<8) + col];
        else if (c<4) v = P.attn[r*512 + ((c-2)<<8) + col];
        else          v = h1r [r*512 + ((c-4)<<8) + col];
      } else {
        if (c<2)      v = h1w [r*512 + (c<<8) + col];
        else          v = h2r [r*512 + ((c-2)<<8) + col];
      }
      xs[r*257 + col] = v;
    }
    __syncthreads();
    const int kc = (c<<8) + (wv<<6);
    for (int kk=0; kk<64; ++kk){
      int k = kc + kk;
      float xv = xs[lane*257 + (wv<<6) + kk];
      const float* wrow;
      if (PHASE==1) wrow = (k<1024) ? (P.ki1 + ((size_t)k<<11))
                                    : (P.kr1 + ((size_t)(k-1024)<<11));
      else          wrow = (k<512)  ? (P.ki2 + ((size_t)k<<11))
                                    : (P.kr2 + ((size_t)(k-512)<<11));
      #pragma unroll
      for (int g=0; g<4; ++g){
        f32x2 w2 = *(const f32x2*)(wrow + (g<<9) + h0);
        acc[g][0] = fmaf(xv, w2[0], acc[g][0]);
        acc[g][1] = fmaf(xv, w2[1], acc[g][1]);
      }
    }
  }
  __syncthreads();
  #pragma unroll
  for (int g=0; g<4; ++g){
    zbuf[((wv<<3) + (g<<1) + 0)*64 + lane] = acc[g][0];
    zbuf[((wv<<3) + (g<<1) + 1)*64 + lane] = acc[g][1];
  }
  __syncthreads();
  if (tid < 128){
    int b = tid & 63, j = tid >> 6;
    const float* bias = (PHASE==1) ? P.b1 : P.b2;
    float zg[4];
    #pragma unroll
    for (int g=0; g<4; ++g){
      int s0 = (g<<1) + j;
      zg[g] = zbuf[s0*64+b] + zbuf[(8+s0)*64+b] + zbuf[(16+s0)*64+b] + zbuf[(24+s0)*64+b]
            + bias[(g<<9) + h0 + j];
    }
    float* cb = (PHASE==1) ? P.c1 : P.c2;
    float* hw = (PHASE==1) ? h1w  : h2w;
    int hidx = b*512 + h0 + j;
    float co = cb[hidx];
    float cn = sigmf(zg[1])*co + sigmf(zg[0])*tanhf(zg[2]);   // i,f,j,o
    float hn = sigmf(zg[3])*tanhf(cn);
    cb[hidx] = cn;
    hw[hidx] = hn;
  }
}

// ======== phase C: q = h2new @ WmT  (K=512, N=1024; WG owns 4 cols) ========
__device__ void qproj_phase(const Params& P, int rp, float* xs, float* zbuf){
  const int wg = blockIdx.x, tid = threadIdx.x;
  const int lane = tid & 63, wv = tid >> 6;
  const int n0 = wg << 2;
  const float* h2n = (rp==0) ? P.h2b : P.h2a;
  float acc[4] = {0.f,0.f,0.f,0.f};
  for (int c=0; c<2; ++c){
    __syncthreads();
    for (int i=tid; i<64*256; i+=NTHR){
      int r = i>>8, col = i&255;
      xs[r*257 + col] = h2n[r*512 + (c<<8) + col];
    }
    __syncthreads();
    const int kc = (c<<8) + (wv<<6);
    for (int kk=0; kk<64; ++kk){
      float xv = xs[lane*257 + (wv<<6) + kk];
      f32x4 w4 = *(const f32x4*)(P.WmT + (((size_t)(kc+kk))<<10) + n0);
      #pragma unroll
      for (int j=0; j<4; ++j) acc[j] = fmaf(xv, w4[j], acc[j]);
    }
  }
  __syncthreads();
  #pragma unroll
  for (int j=0; j<4; ++j) zbuf[((wv<<2)+j)*64 + lane] = acc[j];
  __syncthreads();
  {
    int b = tid & 63, j = tid >> 6;
    float s = zbuf[j*64+b] + zbuf[(4+j)*64+b] + zbuf[(8+j)*64+b] + zbuf[(12+j)*64+b];
    P.q[(b<<10) + n0 + j] = s;
  }
}

// ======== phase D: flash attention partials; WG (b, sg) handles 128 s-rows ========
__device__ void attn_partial(const Params& P, float* smem){
  const int wg = blockIdx.x;
  const int b  = wg >> 2, sg = wg & 3;
  const int tid = threadIdx.x, lane = tid & 63, wv = tid >> 6;

  const float* qp = P.q + (b<<10) + (lane<<4);
  float qf[16];
  #pragma unroll
  for (int j=0; j<16; ++j) qf[j] = qp[j];

  float m = -1e30f, l = 0.f, cx[16];
  #pragma unroll
  for (int j=0; j<16; ++j) cx[j] = 0.f;

  const int sbase = (sg<<7) + (wv<<5);         // 32 rows per wave
  const float* ep0 = P.enc + ((((size_t)b<<9) + sbase)<<10) + (lane<<4);
  f32x4 e0 = *(const f32x4*)(ep0);
  f32x4 e1 = *(const f32x4*)(ep0+4);
  f32x4 e2 = *(const f32x4*)(ep0+8);
  f32x4 e3 = *(const f32x4*)(ep0+12);
  for (int i=0; i<32; ++i){
    f32x4 n0=e0, n1=e1, n2=e2, n3=e3;
    if (i < 31){
      const float* ep = ep0 + ((size_t)(i+1)<<10);
      e0 = *(const f32x4*)(ep);
      e1 = *(const f32x4*)(ep+4);
      e2 = *(const f32x4*)(ep+8);
      e3 = *(const f32x4*)(ep+12);
    }
    float ef[16];
    #pragma unroll
    for (int j=0; j<4; ++j){ ef[j]=n0[j]; ef[4+j]=n1[j]; ef[8+j]=n2[j]; ef[12+j]=n3[j]; }
    float d = 0.f;
    #pragma unroll
    for (int j=0; j<16; ++j) d = fmaf(ef[j], qf[j], d);
    d += __shfl_xor(d, 1, 64);  d += __shfl_xor(d, 2, 64);
    d += __shfl_xor(d, 4, 64);  d += __shfl_xor(d, 8, 64);
    d += __shfl_xor(d, 16, 64); d += __shfl_xor(d, 32, 64);
    int s = sbase + i;
    float sc = d + P.mask[(b<<9)+s] * (-1e9f);
    float mn = fmaxf(m, sc);
    float fs = __expf(m - mn);
    float e  = __expf(sc - mn);
    l = l*fs + e;
    #pragma unroll
    for (int j=0; j<16; ++j) cx[j] = cx[j]*fs + e*ef[j];
    m = mn;
  }
  float* cpart = smem;          // [4][1024]
  float* ml    = smem + 4096;   // [4][2]
  #pragma unroll
  for (int j=0; j<16; ++j) cpart[(wv<<10) + (lane<<4) + j] = cx[j];
  if (lane == 0){ ml[wv*2] = m; ml[wv*2+1] = l; }
  __syncthreads();
  float M = fmaxf(fmaxf(ml[0], ml[2]), fmaxf(ml[4], ml[6]));
  float ew[4]; float L = 0.f;
  #pragma unroll
  for (int v=0; v<4; ++v){ ew[v] = __expf(ml[v*2]-M); L += ew[v]*ml[v*2+1]; }
  float* pp = P.part + (size_t)wg * 1032;
  for (int k=tid; k<1024; k+=NTHR){
    float c = ew[0]*cpart[k] + ew[1]*cpart[1024+k] + ew[2]*cpart[2048+k] + ew[3]*cpart[3072+k];
    pp[2+k] = c;
  }
  if (tid == 0){ pp[0] = M; pp[1] = L; }
}

// ======== phase E: attn = [h2new, ctx] @ Wa; ctx combined during staging ========
__device__ void out_phase(const Params& P, int t, int rp, float* xs, float* zbuf, float* ewn){
  const int wg = blockIdx.x, tid = threadIdx.x;
  const int lane = tid & 63, wv = tid >> 6;
  const int n0 = wg << 1;
  const float* h2n = (rp==0) ? P.h2b : P.h2a;

  if (tid < 64){                 // per-b softmax combine factors (already /L)
    int b = tid;
    const float* p0 = P.part + (size_t)(b*4+0)*1032;
    const float* p1 = P.part + (size_t)(b*4+1)*1032;
    const float* p2 = P.part + (size_t)(b*4+2)*1032;
    const float* p3 = P.part + (size_t)(b*4+3)*1032;
    float M0=p0[0], M1=p1[0], M2=p2[0], M3=p3[0];
    float M = fmaxf(fmaxf(M0,M1), fmaxf(M2,M3));
    float w0=__expf(M0-M), w1=__expf(M1-M), w2=__expf(M2-M), w3=__expf(M3-M);
    float L = w0*p0[1] + w1*p1[1] + w2*p2[1] + w3*p3[1];
    float inv = 1.f / L;
    ewn[b*4+0]=w0*inv; ewn[b*4+1]=w1*inv; ewn[b*4+2]=w2*inv; ewn[b*4+3]=w3*inv;
  }

  float acc[2] = {0.f, 0.f};
  for (int c=0; c<6; ++c){
    __syncthreads();
    for (int i=tid; i<64*256; i+=NTHR){
      int r = i>>8, col = i&255;
      float v;
      if (c < 2){
        v = h2n[r*512 + (c<<8) + col];
      } else {
        int d = ((c-2)<<8) + col;
        const float* pb = P.part + (size_t)(r*4)*1032 + 2 + d;
        v = ewn[r*4+0]*pb[0] + ewn[r*4+1]*pb[1032]
          + ewn[r*4+2]*pb[2064] + ewn[r*4+3]*pb[3096];
      }
      xs[r*257 + col] = v;
    }
    __syncthreads();
    const int kc = (c<<8) + (wv<<6);
    for (int kk=0; kk<64; ++kk){
      float xv = xs[lane*257 + (wv<<6) + kk];
      f32x2 w2 = *(const f32x2*)(P.Wa + (((size_t)(kc+kk))<<9) + n0);
      acc[0] = fmaf(xv, w2[0], acc[0]);
      acc[1] = fmaf(xv, w2[1], acc[1]);
    }
  }
  __syncthreads();
  zbuf[((wv<<1)+0)*64 + lane] = acc[0];
  zbuf[((wv<<1)+1)*64 + lane] = acc[1];
  __syncthreads();
  if (tid < 128){
    int b = tid & 63, j = tid >> 6;
    float s = zbuf[j*64+b] + zbuf[(2+j)*64+b] + zbuf[(4+j)*64+b] + zbuf[(6+j)*64+b];
    int n = n0 + j;
    P.out[(((size_t)b*256 + t)<<9) + n] = s;
    P.attn[b*512 + n] = s;
  }
}

// ======== main persistent kernel ========
__global__ __launch_bounds__(NTHR)
void seq_main(Params P){
  __shared__ float smem[18752];          // 75 KB
  float* xs   = smem;                    // [64][257]
  float* zbuf = smem + 16448;            // [32][64] max
  float* ewn  = smem + 18496;            // [64][4]
  #pragma clang loop unroll(disable)
  for (int t=0; t<256; ++t){
    const int rp = t & 1;
    lstm_phase<1>(P, t, rp, xs, zbuf);  gbar(P.cnt, P.gen);
    lstm_phase<2>(P, t, rp, xs, zbuf);  gbar(P.cnt, P.gen);
    qproj_phase(P, rp, xs, zbuf);       gbar(P.cnt, P.gen);
    attn_partial(P, smem);              gbar(P.cnt, P.gen);
    out_phase(P, t, rp, xs, zbuf, ewn); gbar(P.cnt, P.gen);
  }
}

// ======== prep kernels ========
__global__ void transpose_wm(const float* Wm, float* WmT){
  // Wm [1024][512] -> WmT [512][1024]
  for (size_t idx = (size_t)blockIdx.x*blockDim.x + threadIdx.x; idx < 512*1024;
       idx += (size_t)gridDim.x*blockDim.x){
    int k = (int)(idx >> 10), n = (int)(idx & 1023);
    WmT[idx] = Wm[((size_t)n<<9) + k];
  }
}

__global__ void init_state(const float* fwh, const float* fwc, const float* bwh, const float* bwc,
                           float* h1, float* h2, float* c1, float* c2, float* attn,
                           unsigned* cnt, unsigned* gen){
  int i = blockIdx.x*blockDim.x + threadIdx.x;
  if (i < 64*512){
    h1[i] = fwh[i];
    h2[i] = bwh[i];
    c1[i] = fwc[i];
    c2[i] = bwc[i];
    attn[i] = 0.f;
  }
  if (i == 0){ *cnt = 0u; *gen = 0u; }
}

extern "C" void kernel_launch(void* const* d_in, const int* in_sizes, int n_in,
                              void* d_out, int out_size, void* d_ws, size_t ws_size,
                              hipStream_t stream){
  if (n_in < 15) return;
  const float* tgt = (const float*)d_in[0];
  const float* fwh = (const float*)d_in[1];
  const float* fwc = (const float*)d_in[2];
  const float* bwh = (const float*)d_in[3];
  const float* bwc = (const float*)d_in[4];
  const float* enc = (const float*)d_in[5];
  const float* msk = (const float*)d_in[6];
  const float* Wm  = (const float*)d_in[7];
  const float* Wa  = (const float*)d_in[8];
  const float* ki1 = (const float*)d_in[9];
  const float* kr1 = (const float*)d_in[10];
  const float* b1  = (const float*)d_in[11];
  const float* ki2 = (const float*)d_in[12];
  const float* kr2 = (const float*)d_in[13];
  const float* b2  = (const float*)d_in[14];

  char* w = (char*)d_ws;
  size_t o = 0;
  auto carve = [&](size_t bytes)->char*{
    char* r = w + o; o = (o + bytes + 255) & ~(size_t)255; return r;
  };
  float* WmT  = (float*)carve(512ull*1024*4);
  float* h1a  = (float*)carve(64ull*512*4);
  float* h1b  = (float*)carve(64ull*512*4);
  float* h2a  = (float*)carve(64ull*512*4);
  float* h2b  = (float*)carve(64ull*512*4);
  float* attn = (float*)carve(64ull*512*4);
  float* q    = (float*)carve(64ull*1024*4);
  float* c1   = (float*)carve(64ull*512*4);
  float* c2   = (float*)carve(64ull*512*4);
  float* part = (float*)carve(256ull*1032*4);
  unsigned* cnt = (unsigned*)carve(128);
  unsigned* gen = (unsigned*)carve(128);
  if (o > ws_size) return;   // ~5 MB needed

  hipLaunchKernelGGL(transpose_wm, dim3(512), dim3(256), 0, stream, Wm, WmT);
  hipLaunchKernelGGL(init_state, dim3(128), dim3(256), 0, stream,
                     fwh, fwc, bwh, bwc, h1a, h2a, c1, c2, attn, cnt, gen);

  Params P;
  P.tgt = tgt; P.mask = msk;
  P.ki1 = ki1; P.kr1 = kr1; P.b1 = b1;
  P.ki2 = ki2; P.kr2 = kr2; P.b2 = b2;
  P.Wa = Wa; P.WmT = WmT; P.enc = enc;
  P.h1a = h1a; P.h1b = h1b; P.h2a = h2a; P.h2b = h2b;
  P.attn = attn; P.q = q; P.c1 = c1; P.c2 = c2; P.part = part;
  P.cnt = cnt; P.gen = gen;
  P.out = (float*)d_out;

  hipLaunchKernelGGL(seq_main, dim3(NWG), dim3(NTHR), 0, stream, P);
}

// Round 4
// 39578.775 us; speedup vs baseline: 2.9964x; 2.9964x over previous
//
#include <hip/hip_runtime.h>
#include <stdint.h>

// Seq2Seq decoder (2-layer LSTM + Luong attention), B=64, T=256, S=512, H=512.
// Round 4: all-f32 (proven precision) with:
//  - weights resident in LDS (101 KB/WG, loaded once, zero per-step weight traffic)
//  - transposed-4 activation layout [k/4][b][4] -> all activation loads 1KB/wave coalesced
//  - 512 threads/WG (8 waves/CU), wave = K-slice, LDS partial reduce
//  - phase D (enc stream) 2-row prefetch, 16 rows/wave
// Phases per step: A(LSTM1) B(LSTM2) C(q-proj) D(attn partials) D2(ctx combine) E(out proj)

typedef float f32x4 __attribute__((ext_vector_type(4)));

#define NWG  256
#define NTHR 512

// LDS float offsets
#define OFF_W1 0        // 8 x 1536
#define OFF_W2 12288    // 8 x 1024
#define OFF_WM 20480    // 4 x 512
#define OFF_WA 22528    // 2 x 1536
#define OFF_ZB 25600    // 8192 floats (zbuf / cpart)
#define OFF_ML 33792    // 16 floats
#define SMEM_F 33824    // 135,296 B

struct Params {
  const float* tgtT4;   // [256][128][64][4]
  const float* mask;    // [64][512]
  const float* b1;      // [2048]
  const float* b2;      // [2048]
  const float* Wm;      // [1024][512] raw input (rows = q-col weights)
  const float* enc;     // [64][512][1024] raw input f32
  const float* W1T;     // [2048][1536]
  const float* W2T;     // [2048][1024]
  const float* WaT;     // [512][1536]
  float *h1a,*h1b,*h2a,*h2b;   // T4 [128][64][4]
  float *attnT4;               // T4 [128][64][4]
  float *ctxT4;                // T4 [256][64][4]
  float *q;                    // [64][1024]
  float *c1,*c2;               // [64][512]
  float *part;                 // [256][1032] (M,L,ctx[1024])
  unsigned *cnt,*gen;
  float *out;                  // [64][256][512]
};

__device__ __forceinline__ float sigmf(float x){ return 1.f/(1.f+__expf(-x)); }

// -------- grid barrier (device scope; 256 WGs, 1/CU, co-resident) --------
__device__ void gbar(unsigned* cnt, unsigned* gen){
  __syncthreads();
  if (threadIdx.x == 0){
    unsigned g = __hip_atomic_load(gen, __ATOMIC_RELAXED, __HIP_MEMORY_SCOPE_AGENT);
    unsigned a = __hip_atomic_fetch_add(cnt, 1u, __ATOMIC_ACQ_REL, __HIP_MEMORY_SCOPE_AGENT) + 1u;
    if (a == NWG){
      __hip_atomic_store(cnt, 0u, __ATOMIC_RELAXED, __HIP_MEMORY_SCOPE_AGENT);
      __hip_atomic_fetch_add(gen, 1u, __ATOMIC_RELEASE, __HIP_MEMORY_SCOPE_AGENT);
    } else {
      while (__hip_atomic_load(gen, __ATOMIC_ACQUIRE, __HIP_MEMORY_SCOPE_AGENT) == g)
        __builtin_amdgcn_s_sleep(2);
    }
  }
  __syncthreads();
}

// -------- GEMM core: out[c][b] += sum_k act[k][b] * wL[c][k] --------
// lane = b; wave wv owns kg in [wv*KGW, (wv+1)*KGW); segment select on kg>>7.
// seg pointers pre-offset so addr = seg + kg*256 + lane*4 works with GLOBAL kg.
template<int NCOLS, int KGW>
__device__ __forceinline__ void mm_core(const float* seg0, const float* seg1, const float* seg2,
                                        const float* wL, float* zb, int lane, int wv){
  float acc[NCOLS];
  #pragma unroll
  for (int c=0;c<NCOLS;++c) acc[c]=0.f;
  const int kg0 = wv*KGW;
  #pragma unroll 4
  for (int i=0;i<KGW;++i){
    const int kg = kg0 + i;
    const float* bp = (kg<128) ? seg0 : ((kg<256) ? seg1 : seg2);
    f32x4 a = *(const f32x4*)(bp + ((size_t)kg<<8) + (lane<<2));
    #pragma unroll
    for (int c=0;c<NCOLS;++c){
      f32x4 w = *(const f32x4*)(wL + c*(KGW*32) + (kg<<2));
      acc[c] = fmaf(a[0],w[0],acc[c]); acc[c] = fmaf(a[1],w[1],acc[c]);
      acc[c] = fmaf(a[2],w[2],acc[c]); acc[c] = fmaf(a[3],w[3],acc[c]);
    }
  }
  #pragma unroll
  for (int c=0;c<NCOLS;++c) zb[(wv*NCOLS+c)*64 + lane] = acc[c];
}

// -------- phases A/B: LSTM layers --------
template<int PHASE>
__device__ void lstm_phase(const Params& P, int t, int rp, float* smem){
  const int wg=blockIdx.x, tid=threadIdx.x, lane=tid&63, wv=tid>>6;
  const float* h1r = rp ? P.h1b : P.h1a;
  float*       h1w = rp ? P.h1a : P.h1b;
  const float* h2r = rp ? P.h2b : P.h2a;
  float*       h2w = rp ? P.h2a : P.h2b;

  if (PHASE==1){
    const float* seg0 = P.tgtT4 + ((size_t)t<<15);
    const float* seg1 = P.attnT4 - 32768;
    const float* seg2 = h1r - 65536;
    mm_core<8,48>(seg0, seg1, seg2, smem+OFF_W1, smem+OFF_ZB, lane, wv);
  } else {
    const float* seg0 = h1w;               // h1 NEW
    const float* seg1 = h2r - 32768;       // h2 old
    mm_core<8,32>(seg0, seg1, seg1, smem+OFF_W2, smem+OFF_ZB, lane, wv);
  }
  __syncthreads();
  if (tid < 128){
    const int b = tid&63, j = tid>>6;
    const int h = (wg<<1)+j;
    const float* zb = smem+OFF_ZB;
    const float* bias = (PHASE==1) ? P.b1 : P.b2;
    float z[4];
    #pragma unroll
    for (int g=0; g<4; ++g){
      const int gc = g*2 + j;
      float s = 0.f;
      #pragma unroll
      for (int w=0; w<8; ++w) s += zb[(w*8+gc)*64 + b];
      z[g] = s + bias[(g<<9)+h];
    }
    float* cb = (PHASE==1) ? P.c1 : P.c2;
    float* hw = (PHASE==1) ? h1w  : h2w;
    const int ci = (b<<9)+h;
    float co = cb[ci];
    float cn = sigmf(z[1])*co + sigmf(z[0])*tanhf(z[2]);   // i,f,j,o
    float hn = sigmf(z[3])*tanhf(cn);
    cb[ci] = cn;
    hw[((h>>2)<<8) + (b<<2) + (h&3)] = hn;
  }
}

// -------- phase C: q = h2new @ Wm^T --------
__device__ void qproj_phase(const Params& P, int rp, float* smem){
  const int wg=blockIdx.x, tid=threadIdx.x, lane=tid&63, wv=tid>>6;
  const float* h2n = rp ? P.h2a : P.h2b;
  mm_core<4,16>(h2n, h2n, h2n, smem+OFF_WM, smem+OFF_ZB, lane, wv);
  __syncthreads();
  if (tid < 256){
    const int b = tid&63, j = tid>>6;
    const float* zb = smem+OFF_ZB;
    float s = 0.f;
    #pragma unroll
    for (int w=0; w<8; ++w) s += zb[(w*4+j)*64 + b];
    P.q[(b<<10) + (wg<<2) + j] = s;
  }
}

// -------- phase D: flash attention partials; WG(b,sg); wave=16 s-rows --------
__device__ void attn_phase(const Params& P, float* cpart, float* ml){
  const int wg=blockIdx.x, tid=threadIdx.x, lane=tid&63, wv=tid>>6;
  const int b = wg>>2, sg = wg&3;
  const float* qp = P.q + (b<<10) + (lane<<4);
  f32x4 q0 = *(const f32x4*)qp,     q1 = *(const f32x4*)(qp+4),
        q2 = *(const f32x4*)(qp+8), q3 = *(const f32x4*)(qp+12);
  const int s0 = (sg<<7) + (wv<<4);
  const float* ep = P.enc + ((((size_t)b<<9) + s0)<<10) + (lane<<4);
  const float* mk = P.mask + (b<<9) + s0;
  f32x4 a0,a1,a2,a3, p0,p1,p2,p3;
  a0=*(const f32x4*)ep; a1=*(const f32x4*)(ep+4); a2=*(const f32x4*)(ep+8); a3=*(const f32x4*)(ep+12);
  const float* ep1 = ep + 1024;
  p0=*(const f32x4*)ep1; p1=*(const f32x4*)(ep1+4); p2=*(const f32x4*)(ep1+8); p3=*(const f32x4*)(ep1+12);
  float m = -1e30f, l = 0.f;
  f32x4 cx0={0,0,0,0}, cx1={0,0,0,0}, cx2={0,0,0,0}, cx3={0,0,0,0};
  for (int i=0;i<16;++i){
    f32x4 e0=a0, e1=a1, e2=a2, e3=a3;
    a0=p0; a1=p1; a2=p2; a3=p3;
    if (i<14){
      const float* ep2 = ep + (size_t)(i+2)*1024;
      p0=*(const f32x4*)ep2; p1=*(const f32x4*)(ep2+4); p2=*(const f32x4*)(ep2+8); p3=*(const f32x4*)(ep2+12);
    }
    float d = 0.f;
    #pragma unroll
    for (int j=0;j<4;++j){
      d = fmaf(e0[j],q0[j],d); d = fmaf(e1[j],q1[j],d);
      d = fmaf(e2[j],q2[j],d); d = fmaf(e3[j],q3[j],d);
    }
    d += __shfl_xor(d,1,64);  d += __shfl_xor(d,2,64);  d += __shfl_xor(d,4,64);
    d += __shfl_xor(d,8,64);  d += __shfl_xor(d,16,64); d += __shfl_xor(d,32,64);
    float sc = d + mk[i]*(-1e9f);
    float mn = fmaxf(m, sc);
    float fs = __expf(m - mn), e = __expf(sc - mn);
    l = l*fs + e;
    #pragma unroll
    for (int j=0;j<4;++j){
      cx0[j] = cx0[j]*fs + e*e0[j]; cx1[j] = cx1[j]*fs + e*e1[j];
      cx2[j] = cx2[j]*fs + e*e2[j]; cx3[j] = cx3[j]*fs + e*e3[j];
    }
    m = mn;
  }
  float* cp = cpart + (wv<<10) + (lane<<4);
  *(f32x4*)cp = cx0; *(f32x4*)(cp+4)=cx1; *(f32x4*)(cp+8)=cx2; *(f32x4*)(cp+12)=cx3;
  if (lane==0){ ml[wv*2]=m; ml[wv*2+1]=l; }
  __syncthreads();
  float M = -1e30f;
  #pragma unroll
  for (int w=0;w<8;++w) M = fmaxf(M, ml[w*2]);
  float ew[8]; float L = 0.f;
  #pragma unroll
  for (int w=0;w<8;++w){ ew[w] = __expf(ml[w*2]-M); L += ew[w]*ml[w*2+1]; }
  float* pp = P.part + (size_t)wg*1032;
  for (int k=tid; k<1024; k+=NTHR){
    float c = 0.f;
    #pragma unroll
    for (int w=0;w<8;++w) c = fmaf(ew[w], cpart[(w<<10)+k], c);
    pp[2+k] = c;
  }
  if (tid==0){ pp[0]=M; pp[1]=L; }
}

// -------- phase D2: combine 4 s-group partials -> ctxT4 --------
__device__ void ctx_phase(const Params& P){
  const int wg=blockIdx.x, tid=threadIdx.x;
  const int b = wg>>2, dq = wg&3;
  if (tid < 256){
    const int d = (dq<<8) + tid;
    const float* pb = P.part + ((size_t)(b<<2))*1032;
    float M0=pb[0],    L0=pb[1];
    float M1=pb[1032], L1=pb[1033];
    float M2=pb[2064], L2=pb[2065];
    float M3=pb[3096], L3=pb[3097];
    float M = fmaxf(fmaxf(M0,M1), fmaxf(M2,M3));
    float w0=__expf(M0-M), w1=__expf(M1-M), w2=__expf(M2-M), w3=__expf(M3-M);
    float inv = 1.f/(w0*L0 + w1*L1 + w2*L2 + w3*L3);
    float c = (w0*pb[2+d] + w1*pb[1034+d] + w2*pb[2066+d] + w3*pb[3098+d]) * inv;
    P.ctxT4[((d>>2)<<8) + (b<<2) + (d&3)] = c;
  }
}

// -------- phase E: attn = [h2new, ctx] @ Wa --------
__device__ void out_phase(const Params& P, int t, int rp, float* smem){
  const int wg=blockIdx.x, tid=threadIdx.x, lane=tid&63, wv=tid>>6;
  const float* h2n = rp ? P.h2a : P.h2b;
  const float* seg1 = P.ctxT4 - 32768;
  mm_core<2,48>(h2n, seg1, seg1, smem+OFF_WA, smem+OFF_ZB, lane, wv);
  __syncthreads();
  if (tid < 128){
    const int b = tid&63, j = tid>>6;
    const float* zb = smem+OFF_ZB;
    float s = 0.f;
    #pragma unroll
    for (int w=0;w<8;++w) s += zb[(w*2+j)*64 + b];
    const int n = (wg<<1)+j;
    P.out[(((size_t)b<<8) + t)*512 + n] = s;
    P.attnT4[((n>>2)<<8) + (b<<2) + (n&3)] = s;
  }
}

// -------- one-time: weights -> LDS --------
__device__ void load_weights(const Params& P, float* smem){
  const int wg=blockIdx.x, tid=threadIdx.x;
  #pragma unroll
  for (int c=0;c<8;++c){
    const int n = ((c>>1)<<9) + (wg<<1) + (c&1);
    const float* src = P.W1T + (size_t)n*1536;
    float* dst = smem + OFF_W1 + c*1536;
    for (int i=tid;i<1536;i+=NTHR) dst[i]=src[i];
  }
  #pragma unroll
  for (int c=0;c<8;++c){
    const int n = ((c>>1)<<9) + (wg<<1) + (c&1);
    const float* src = P.W2T + (size_t)n*1024;
    float* dst = smem + OFF_W2 + c*1024;
    for (int i=tid;i<1024;i+=NTHR) dst[i]=src[i];
  }
  #pragma unroll
  for (int c=0;c<4;++c){
    const int n = (wg<<2)+c;
    const float* src = P.Wm + (size_t)n*512;
    float* dst = smem + OFF_WM + c*512;
    for (int i=tid;i<512;i+=NTHR) dst[i]=src[i];
  }
  #pragma unroll
  for (int c=0;c<2;++c){
    const int n = (wg<<1)+c;
    const float* src = P.WaT + (size_t)n*1536;
    float* dst = smem + OFF_WA + c*1536;
    for (int i=tid;i<1536;i+=NTHR) dst[i]=src[i];
  }
  __syncthreads();
}

// -------- main persistent kernel --------
__global__ __launch_bounds__(NTHR, 2)
void seq_main(Params P){
  __shared__ float smem[SMEM_F];
  load_weights(P, smem);
  #pragma clang loop unroll(disable)
  for (int t=0; t<256; ++t){
    const int rp = t&1;
    lstm_phase<1>(P, t, rp, smem);           gbar(P.cnt,P.gen);
    lstm_phase<2>(P, t, rp, smem);           gbar(P.cnt,P.gen);
    qproj_phase(P, rp, smem);                gbar(P.cnt,P.gen);
    attn_phase(P, smem+OFF_ZB, smem+OFF_ML); gbar(P.cnt,P.gen);
    ctx_phase(P);                            gbar(P.cnt,P.gen);
    out_phase(P, t, rp, smem);               gbar(P.cnt,P.gen);
  }
}

// ======== prep kernels ========
// dst[n*K + k] = src(k,n), src(k,n) = k<KA ? a[k*N+n] : b[(k-KA)*N+n]
__global__ void transT(const float* a, const float* bsrc, float* dst, int K, int N, int KA){
  __shared__ float tile[32][33];
  const int ntk = K>>5;
  const int tn = blockIdx.x / ntk, tk = blockIdx.x - tn*ntk;
  const int tid = threadIdx.x;
  const int c = tid & 31, r = tid >> 5;
  for (int rr=r; rr<32; rr+=8){
    const int k = (tk<<5)+rr, n = (tn<<5)+c;
    tile[rr][c] = (k<KA) ? a[(size_t)k*N+n] : bsrc[(size_t)(k-KA)*N+n];
  }
  __syncthreads();
  for (int rr=r; rr<32; rr+=8){
    const int n = (tn<<5)+rr, k = (tk<<5)+c;
    dst[(size_t)n*K + k] = tile[c][rr];
  }
}

// tgt[b][t][k] -> tgtT4[t][k>>2][b][k&3]
__global__ void prep_tgt(const float* tgt, float* tgtT4){
  __shared__ float xt[64*517];
  const int t = blockIdx.x, tid = threadIdx.x;   // 256 threads
  for (int i=tid; i<64*512; i+=256){
    const int bb = i>>9, k = i&511;
    xt[bb*517 + k] = tgt[((size_t)bb*256 + t)*512 + k];
  }
  __syncthreads();
  for (int i=tid; i<128*64; i+=256){
    const int kg = i>>6, bb = i&63;
    f32x4 v = { xt[bb*517 + kg*4], xt[bb*517 + kg*4 + 1],
                xt[bb*517 + kg*4 + 2], xt[bb*517 + kg*4 + 3] };
    *(f32x4*)(tgtT4 + ((size_t)t<<15) + (kg<<8) + (bb<<2)) = v;
  }
}

__global__ void init_state(const float* fwh, const float* fwc, const float* bwh, const float* bwc,
                           float* h1a, float* h2a, float* attnT4, float* c1, float* c2,
                           unsigned* cnt, unsigned* gen){
  const int i = blockIdx.x*blockDim.x + threadIdx.x;
  if (i < 64*512){
    const int bb = i>>9, k = i&511;
    const int t4 = ((k>>2)<<8) + (bb<<2) + (k&3);
    h1a[t4] = fwh[i];
    h2a[t4] = bwh[i];
    attnT4[t4] = 0.f;
    c1[i] = fwc[i];
    c2[i] = bwc[i];
  }
  if (i == 0){ *cnt = 0u; *gen = 0u; }
}

extern "C" void kernel_launch(void* const* d_in, const int* in_sizes, int n_in,
                              void* d_out, int out_size, void* d_ws, size_t ws_size,
                              hipStream_t stream){
  if (n_in < 15) return;
  const float* tgt = (const float*)d_in[0];
  const float* fwh = (const float*)d_in[1];
  const float* fwc = (const float*)d_in[2];
  const float* bwh = (const float*)d_in[3];
  const float* bwc = (const float*)d_in[4];
  const float* enc = (const float*)d_in[5];
  const float* msk = (const float*)d_in[6];
  const float* Wm  = (const float*)d_in[7];
  const float* Wa  = (const float*)d_in[8];
  const float* ki1 = (const float*)d_in[9];
  const float* kr1 = (const float*)d_in[10];
  const float* b1  = (const float*)d_in[11];
  const float* ki2 = (const float*)d_in[12];
  const float* kr2 = (const float*)d_in[13];
  const float* b2  = (const float*)d_in[14];

  char* w = (char*)d_ws;
  size_t o = 0;
  auto carve = [&](size_t bytes)->char*{
    char* r = w + o; o = (o + bytes + 255) & ~(size_t)255; return r;
  };
  float* W1T   = (float*)carve(2048ull*1536*4);
  float* W2T   = (float*)carve(2048ull*1024*4);
  float* WaT   = (float*)carve(512ull*1536*4);
  float* tgtT4 = (float*)carve(256ull*128*256*4);
  float* h1a   = (float*)carve(128ull*256*4);
  float* h1b   = (float*)carve(128ull*256*4);
  float* h2a   = (float*)carve(128ull*256*4);
  float* h2b   = (float*)carve(128ull*256*4);
  float* attnT4= (float*)carve(128ull*256*4);
  float* ctxT4 = (float*)carve(256ull*256*4);
  float* q     = (float*)carve(64ull*1024*4);
  float* c1    = (float*)carve(64ull*512*4);
  float* c2    = (float*)carve(64ull*512*4);
  float* part  = (float*)carve(256ull*1032*4);
  unsigned* cnt = (unsigned*)carve(128);
  unsigned* gen = (unsigned*)carve(128);
  if (o > ws_size) return;   // ~61 MB needed

  hipLaunchKernelGGL(transT, dim3(64*48), dim3(256), 0, stream, ki1, kr1, W1T, 1536, 2048, 1024);
  hipLaunchKernelGGL(transT, dim3(64*32), dim3(256), 0, stream, ki2, kr2, W2T, 1024, 2048, 512);
  hipLaunchKernelGGL(transT, dim3(16*48), dim3(256), 0, stream, Wa,  Wa,  WaT, 1536, 512, 1536);
  hipLaunchKernelGGL(prep_tgt, dim3(256), dim3(256), 0, stream, tgt, tgtT4);
  hipLaunchKernelGGL(init_state, dim3(128), dim3(256), 0, stream,
                     fwh, fwc, bwh, bwc, h1a, h2a, attnT4, c1, c2, cnt, gen);

  Params P;
  P.tgtT4 = tgtT4; P.mask = msk; P.b1 = b1; P.b2 = b2;
  P.Wm = Wm; P.enc = enc;
  P.W1T = W1T; P.W2T = W2T; P.WaT = WaT;
  P.h1a = h1a; P.h1b = h1b; P.h2a = h2a; P.h2b = h2b;
  P.attnT4 = attnT4; P.ctxT4 = ctxT4; P.q = q;
  P.c1 = c1; P.c2 = c2; P.part = part;
  P.cnt = cnt; P.gen = gen;
  P.out = (float*)d_out;

  hipLaunchKernelGGL(seq_main, dim3(NWG), dim3(NTHR), 0, stream, P);
}